// Round 8
// baseline (69.942 us; speedup 1.0000x reference)
//
#include <hip/hip_runtime.h>
#include <hip/hip_bf16.h>

// ws layout (requires ws_size >= 17039360 B):
//   [0, 221184)        : weights as bf16 in 16x16x32 MFMA B-fragment order
//   [221184, 221440)   : 256 B of zeros (OOB halo source)
//   [262144, 17039360) : x_t = x transposed to [b][s][c] bf16 (16 MiB)
#define WS_W_OFF    0
#define WS_ZERO_OFF 221184
#define WS_XT_OFF   262144

typedef __attribute__((ext_vector_type(8))) short s16x8;
typedef __attribute__((ext_vector_type(4))) float f32x4;

#define GLOBAL_AS __attribute__((address_space(1)))
#define LDS_AS    __attribute__((address_space(3)))

__device__ __forceinline__ unsigned short f2bf(float f) {
  unsigned u = __builtin_bit_cast(unsigned, f);
  u = u + 0x7fffu + ((u >> 16) & 1u);
  return (unsigned short)(u >> 16);
}

// ---------------------------------------------------------------------------
// Fused prep (identical to round-5): blocks [0,432) repack weights;
// blocks [432,4528) transpose x to channels-last bf16.
// Fragment f = (tap*2+h)*4+nf holds B[n][k] for n = nf*16 + (lane&15),
// cin = h*32 + (lane>>4)*8 + j. bf16 index = (f*64 + lane)*8 + j.
__global__ void prep_kernel(const float* __restrict__ x,
                            const float* __restrict__ w,
                            unsigned short* __restrict__ wsw,
                            float* __restrict__ zeros,
                            unsigned short* __restrict__ xt) {
  int blk = blockIdx.x;
  if (blk < 432) {
    int t = blk * 256 + threadIdx.x;             // 110592 threads exactly
    int tap  = t % 27;
    int cin  = (t / 27) & 63;
    int cout = t / (27 * 64);
    int h   = cin >> 5;
    int q   = (cin >> 3) & 3;
    int j   = cin & 7;
    int nf  = cout >> 4;
    int lane = q * 16 + (cout & 15);
    int dst = (((tap * 2 + h) * 4 + nf) * 64 + lane) * 8 + j;
    wsw[dst] = f2bf(w[t]);
    if (t < 64) zeros[t] = 0.0f;
  } else {
    int t  = (blk - 432) * 256 + threadIdx.x;    // 1048576 threads
    int s  = t & 32767;
    int c8 = (t >> 15) & 7;
    int b  = t >> 18;
    const float* src = x + (size_t)(b * 64 + c8 * 8) * 32768 + s;
    s16x8 v;
    #pragma unroll
    for (int k = 0; k < 8; ++k) v[k] = (short)f2bf(src[(size_t)k * 32768]);
    *(s16x8*)(xt + (size_t)(b * 32768 + s) * 64 + c8 * 8) = v;
  }
}

// ---------------------------------------------------------------------------
// Implicit-GEMM conv with cin-SPLIT wave pairs for 4 waves/SIMD TLP.
// Block = (b, z-quad, y-quad): 4z x 4y x 32x = 512 outputs x 64 couts,
// 1024 threads = 16 waves, grid 256 = exactly 1 block/CU (153 KB LDS).
// Wave w: tile t=w>>1 (zi=t>>1, yi=t&1 -> z=z0+zi, y-pair y0+yi*2), h=w&1
// = cin half. Each wave: M_w=64 (2y x 32x), K=32 -> 16 waves/CU = 4/SIMD.
// Total per-CU budgets: MFMA 33.5K cy, B-L1 27K cy, A-LDS 20K cy -> all
// pipes <= wall; 4-wave TLP hides L1/L2/LDS latency (m114 regime).
// Tap loop has ZERO barriers (full-K halo staged once; B from L1/L2 with
// 16-wave lockstep reuse). Pairwise partial-sum reduction via LDS (aliased
// over halo after a barrier), then both waves store disjoint y-rows.
//
// Halo: pos p (of 1224 = 6z*6y*34x) at halo[p*128]; 16B cin-chunk c stored
// at slot c ^ (p&7). A-read (lane l: p = p0+(l&15), c = h*4+(l>>4)) -> each
// 4-bank group serves exactly 8 lanes = b128 floor, conflict-free.
// Staging dest is LINEAR (= halo + r*16384 + tid*16); the swizzle is applied
// to the SOURCE chunk, csrc = (tid&7) ^ ((tid>>3)&7) (constant per thread
// since round base r*128 == 0 mod 8).
__global__ __launch_bounds__(1024, 4) void conv_kernel(const float* __restrict__ bias,
                                                       float* __restrict__ out,
                                                       const char* __restrict__ ws) {
  __shared__ __align__(16) unsigned char halo[1224 * 128];   // 156672 B

  const int tid  = threadIdx.x;
  const int lane = tid & 63;
  const int w    = tid >> 6;                     // wave 0..15
  const int t_   = w >> 1;                       // tile 0..7
  const int h    = w & 1;                        // cin half
  const int zi   = t_ >> 1, yi = t_ & 1;
  // XCD swizzle (256 % 8 == 0 -> bijective): 32 contiguous logical blocks per
  // XCD (fixed b, 4 consecutive z-quads) -> ~2.4 MB x_t slab L2-resident.
  const int logical = (blockIdx.x & 7) * 32 + (blockIdx.x >> 3);
  const int yq = logical & 7, zq = (logical >> 3) & 7, b = logical >> 6;
  const int z0 = zq * 4, y0 = yq * 4;

  const int r15 = lane & 15;
  const int hi4 = lane >> 4;

  // ---- stage full-K halo: 1224 pos x 128 B, 10 rounds x 128 pos ----
  {
    const int csrc = ((tid & 7) ^ ((tid >> 3) & 7)) * 16;
    #pragma unroll 1
    for (int r = 0; r < 10; ++r) {
      int pos = r * 128 + (tid >> 3);
      if (pos < 1224) {
        int hz = pos / 204; int rem = pos - hz * 204;      // 204 = 6*34
        int hy = rem / 34;  int hx = rem - hy * 34;
        int gz = z0 + hz - 1, gy = y0 + hy - 1, gx = hx - 1;
        bool inb = ((unsigned)gz < 32u) & ((unsigned)gy < 32u) &
                   ((unsigned)gx < 32u);
        int s = (gz * 32 + gy) * 32 + gx;
        int src = inb ? (WS_XT_OFF + (b * 32768 + s) * 128 + csrc)
                      : WS_ZERO_OFF;
        __builtin_amdgcn_global_load_lds(
            (const GLOBAL_AS void*)(ws + src),
            (LDS_AS void*)(&halo[r * 16384 + tid * 16]),
            16, 0, 0);
      }
    }
  }

  const s16x8* __restrict__ wfr = (const s16x8*)(ws + WS_W_OFF);

  f32x4 zero4 = {0.f, 0.f, 0.f, 0.f};
  f32x4 acc[4][4];
  #pragma unroll
  for (int mf = 0; mf < 4; ++mf)
    #pragma unroll
    for (int nf = 0; nf < 4; ++nf) acc[mf][nf] = zero4;

  // per-lane invariants for the tap loop
  const int pbase = (zi * 6 + yi * 2) * 34 + r15;  // pos before tap offsets
  const int chunk = h * 4 + hi4;                   // this wave's cin chunk

  __syncthreads();   // drains global_load_lds; halo ready for all waves

  // ---- 27 taps, fully unrolled, zero barriers ----
  #pragma unroll
  for (int tap = 0; tap < 27; ++tap) {
    const int kd = tap / 9, r9 = tap % 9;
    const int kh = r9 / 3, kw = r9 % 3;            // compile-time constants
    s16x8 Bf[4], Af[4];
    #pragma unroll
    for (int nf = 0; nf < 4; ++nf)
      Bf[nf] = wfr[((tap * 2 + h) * 4 + nf) * 64 + lane];
    #pragma unroll
    for (int mf = 0; mf < 4; ++mf) {
      int p = pbase + (kd * 6 + (mf >> 1) + kh) * 34 + kw + (mf & 1) * 16;
      Af[mf] = *(const s16x8*)&halo[p * 128 + ((chunk ^ (p & 7)) << 4)];
    }
    #pragma unroll
    for (int mf = 0; mf < 4; ++mf)
      #pragma unroll
      for (int nf = 0; nf < 4; ++nf)
        acc[mf][nf] = __builtin_amdgcn_mfma_f32_16x16x32_bf16(
            Af[mf], Bf[nf], acc[mf][nf], 0, 0, 0);
  }

  // ---- pairwise K-reduction via LDS (aliased over halo) ----
  // Wave h keeps m-frags {h*2, h*2+1} (its y-row), writes the other two.
  __syncthreads();   // all waves done READING halo
  {
    unsigned char* red = halo;
    const int wrOff = t_ * 16384 + (1 - h) * 8192;
    #pragma unroll
    for (int mfr = 0; mfr < 2; ++mfr)
      #pragma unroll
      for (int nf = 0; nf < 4; ++nf)
        *(f32x4*)&red[wrOff + (mfr * 4 + nf) * 1024 + lane * 16] =
            acc[(1 - h) * 2 + mfr][nf];
  }
  __syncthreads();

  // ---- add partner partials + bias, store own y-row ----
  const int z = z0 + zi;
  const int y = y0 + yi * 2 + h;
  const int rdOff = t_ * 16384 + h * 8192;
  #pragma unroll
  for (int nf = 0; nf < 4; ++nf) {
    int cout = nf * 16 + r15;
    float bv = bias[cout];
    float* orow = out + ((size_t)((b * 64 + cout) * 32 + z) * 32 + y) * 32;
    #pragma unroll
    for (int mfr = 0; mfr < 2; ++mfr) {
      f32x4 part = *(const f32x4*)&halo[rdOff + (mfr * 4 + nf) * 1024 + lane * 16];
      int x0 = mfr * 16 + hi4 * 4;
      f32x4 v;
      #pragma unroll
      for (int r = 0; r < 4; ++r)
        v[r] = acc[h * 2 + mfr][nf][r] + part[r] + bv;
      *(f32x4*)&orow[x0] = v;
    }
  }
}

extern "C" void kernel_launch(void* const* d_in, const int* in_sizes, int n_in,
                              void* d_out, int out_size, void* d_ws, size_t ws_size,
                              hipStream_t stream) {
  const float* x    = (const float*)d_in[0];
  const float* wgt  = (const float*)d_in[1];
  const float* bias = (const float*)d_in[2];
  float* out = (float*)d_out;
  char* ws = (char*)d_ws;

  prep_kernel<<<4528, 256, 0, stream>>>(x, wgt,
                                        (unsigned short*)(ws + WS_W_OFF),
                                        (float*)(ws + WS_ZERO_OFF),
                                        (unsigned short*)(ws + WS_XT_OFF));
  conv_kernel<<<256, 1024, 0, stream>>>(bias, out, ws);
}

// Round 9
// 45.385 us; speedup vs baseline: 1.5411x; 1.5411x over previous
//
#include <hip/hip_runtime.h>
#include <hip/hip_bf16.h>

// ws layout (requires ws_size >= 17039360 B):
//   [0, 221184)        : weights as bf16 in 16x16x32 MFMA B-fragment order
//   [221184, 221440)   : 256 B of zeros (OOB halo source)
//   [262144, 17039360) : x_t = x transposed to [b][s][c] bf16 (16 MiB)
#define WS_W_OFF    0
#define WS_ZERO_OFF 221184
#define WS_XT_OFF   262144

typedef __attribute__((ext_vector_type(8))) short s16x8;
typedef __attribute__((ext_vector_type(4))) float f32x4;

#define GLOBAL_AS __attribute__((address_space(1)))
#define LDS_AS    __attribute__((address_space(3)))

__device__ __forceinline__ unsigned short f2bf(float f) {
  unsigned u = __builtin_bit_cast(unsigned, f);
  u = u + 0x7fffu + ((u >> 16) & 1u);
  return (unsigned short)(u >> 16);
}

// ---------------------------------------------------------------------------
// Fused prep (identical to round-5): blocks [0,432) repack weights;
// blocks [432,4528) transpose x to channels-last bf16.
// Fragment f = (tap*2+h)*4+nf holds B[n][k] for n = nf*16 + (lane&15),
// cin = h*32 + (lane>>4)*8 + j. bf16 index = (f*64 + lane)*8 + j.
__global__ void prep_kernel(const float* __restrict__ x,
                            const float* __restrict__ w,
                            unsigned short* __restrict__ wsw,
                            float* __restrict__ zeros,
                            unsigned short* __restrict__ xt) {
  int blk = blockIdx.x;
  if (blk < 432) {
    int t = blk * 256 + threadIdx.x;             // 110592 threads exactly
    int tap  = t % 27;
    int cin  = (t / 27) & 63;
    int cout = t / (27 * 64);
    int h   = cin >> 5;
    int q   = (cin >> 3) & 3;
    int j   = cin & 7;
    int nf  = cout >> 4;
    int lane = q * 16 + (cout & 15);
    int dst = (((tap * 2 + h) * 4 + nf) * 64 + lane) * 8 + j;
    wsw[dst] = f2bf(w[t]);
    if (t < 64) zeros[t] = 0.0f;
  } else {
    int t  = (blk - 432) * 256 + threadIdx.x;    // 1048576 threads
    int s  = t & 32767;
    int c8 = (t >> 15) & 7;
    int b  = t >> 18;
    const float* src = x + (size_t)(b * 64 + c8 * 8) * 32768 + s;
    s16x8 v;
    #pragma unroll
    for (int k = 0; k < 8; ++k) v[k] = (short)f2bf(src[(size_t)k * 32768]);
    *(s16x8*)(xt + (size_t)(b * 32768 + s) * 64 + c8 * 8) = v;
  }
}

// ---------------------------------------------------------------------------
// Implicit-GEMM conv = round-5 geometry + T4 counted-vmcnt B pipeline.
// Block = (b, z-pair, y-quad): 2z x 4y x 32x = 256 outputs x 64 couts,
// 4 waves. Wave w: z = z0+(w>>1), y-rows {y0+2(w&1),+1}: M_w = 64.
// K = 64 as two cin-halves; halo per half: 4z x 6y x 34x pos x 64 B = 52 KB
// -> grid 512 = 2 blocks/CU (8 waves/CU).
//
// B pipeline: inline-asm global_load_dwordx4 into a 3-slot register rotation,
// issued 2 taps ahead; per-tap `s_waitcnt vmcnt(8)` (4 at tap 25, 0 at 26 --
// never a mid-loop drain) + sched_barrier(0x106) (DS_READ/VALU/SALU may
// cross, MFMA may NOT -- rule #18). B latency is hidden under 2 taps of MFMA
// by construction; compiler cannot sink the loads or insert vmcnt(0).
//
// Halo layout LINEAR: pos p at halo[p*64], cin-chunk c at +c*16. A-read
// (lane l: p += l&15, c = l>>4) puts exactly 8 of the wave's 256 dwords on
// each bank -> ds_read_b128 floor, conflict-free. Staging dest linear.
__global__ __launch_bounds__(256, 2) void conv_kernel(const float* __restrict__ bias,
                                                      float* __restrict__ out,
                                                      const char* __restrict__ ws) {
  __shared__ __align__(16) unsigned char halo[52 * 1024];  // 832 pos (816 used)

  const int tid  = threadIdx.x;
  const int lane = tid & 63;
  const int w    = tid >> 6;                     // wave id 0..3
  // XCD-aware swizzle (512 % 8 == 0 -> bijective): each XCD gets 64 contiguous
  // logical blocks (fixed b, 8 consecutive z-pairs) -> ~2.4 MB x_t slab in L2.
  const int logical = (blockIdx.x & 7) * 64 + (blockIdx.x >> 3);
  const int yt = logical & 7, zt = (logical >> 3) & 15, b = logical >> 7;
  const int z0 = zt * 2, y0 = yt * 4;
  const int zo  = w >> 1;
  const int yo2 = (w & 1) * 2;

  const int r15 = lane & 15;
  const int hi4 = lane >> 4;

  // halo staging: granule = 1024 B = 16 positions; lane l -> pos g*16 + (l>>2),
  // 16B chunk l&3. All linear (dest and source).
  const int sl_sub   = lane >> 2;
  const int sl_chunk = lane & 3;

  auto stage_halo = [&](int h) {
    for (int g = w; g < 52; g += 4) {            // 13 granules per wave
      int pos = g * 16 + sl_sub;
      int hz = pos / 204; int rem = pos - hz * 204;        // 204 = 6*34
      int hy = rem / 34;  int hx = rem - hy * 34;
      int gz = z0 + hz - 1, gy = y0 + hy - 1, gx = hx - 1;
      bool inb = (pos < 816) & ((unsigned)gz < 32u) &
                 ((unsigned)gy < 32u) & ((unsigned)gx < 32u);
      int s = (gz * 32 + gy) * 32 + gx;
      int src = inb ? (WS_XT_OFF + (b * 32768 + s) * 128 + h * 64 + sl_chunk * 16)
                    : WS_ZERO_OFF;
      __builtin_amdgcn_global_load_lds(
          (const GLOBAL_AS void*)(ws + src),
          (LDS_AS void*)(&halo[g * 1024 + lane * 16]),
          16, 0, 0);
    }
  };

  const char* wsb_lane = ws + WS_W_OFF + lane * 16;

  f32x4 zero4 = {0.f, 0.f, 0.f, 0.f};
  f32x4 acc[4][4];
  #pragma unroll
  for (int mf = 0; mf < 4; ++mf)
    #pragma unroll
    for (int nf = 0; nf < 4; ++nf) acc[mf][nf] = zero4;

  s16x8 Bb[3][4];

  // Issue one tap's 4 B-fragment loads (16 B/lane each). Raw asm so the
  // compiler cannot sink them or insert its own vmcnt waits.
  auto issueB = [&](int slot, int h, int tap) {
    const char* bt = wsb_lane + (tap * 2 + h) * 4096;
    asm volatile("global_load_dwordx4 %0, %1, off"             : "=v"(Bb[slot][0]) : "v"(bt));
    asm volatile("global_load_dwordx4 %0, %1, off offset:1024" : "=v"(Bb[slot][1]) : "v"(bt));
    asm volatile("global_load_dwordx4 %0, %1, off offset:2048" : "=v"(Bb[slot][2]) : "v"(bt));
    asm volatile("global_load_dwordx4 %0, %1, off offset:3072" : "=v"(Bb[slot][3]) : "v"(bt));
  };

  // A fragment for tap: mf = (dy = mf>>1, xh = mf&1); lane l reads position
  // base + dy*34 + xh*16 + (l&15), cin-chunk l>>4 (k = (l>>4)*8 + j).
  auto loadA = [&](s16x8* a, int tap) {
    int kd = tap / 9; int r9 = tap - kd * 9;
    int kh = r9 / 3;  int kw = r9 - kh * 3;      // fold under full unroll
    int base = ((zo + kd) * 6 + (yo2 + kh)) * 34 + kw + r15;
    #pragma unroll
    for (int mf = 0; mf < 4; ++mf) {
      int pos = base + (mf >> 1) * 34 + (mf & 1) * 16;
      a[mf] = *(const s16x8*)&halo[pos * 64 + hi4 * 16];
    }
  };

  auto compute = [&](const s16x8* a, const s16x8* B) {
    #pragma unroll
    for (int mf = 0; mf < 4; ++mf)
      #pragma unroll
      for (int nf = 0; nf < 4; ++nf)
        acc[mf][nf] = __builtin_amdgcn_mfma_f32_16x16x32_bf16(
            a[mf], B[nf], acc[mf][nf], 0, 0, 0);
  };

  // 27 taps, fully unrolled; B issued 2 taps ahead; counted waits, no drain.
  auto run27 = [&](int h) {
    #pragma unroll
    for (int tap = 0; tap < 27; ++tap) {
      if (tap < 25) issueB((tap + 2) % 3, h, tap + 2);     // folds to static slot
      if (tap < 25)        { asm volatile("s_waitcnt vmcnt(8)"); }
      else if (tap == 25)  { asm volatile("s_waitcnt vmcnt(4)"); }
      else                 { asm volatile("s_waitcnt vmcnt(0)"); }
      __builtin_amdgcn_sched_barrier(0x106);   // DS_READ|VALU|SALU may cross
      s16x8 Af[4];
      loadA(Af, tap);
      compute(Af, Bb[tap % 3]);
    }
  };

  stage_halo(0);
  issueB(0, 0, 0); issueB(1, 0, 1);  // overlaps halo staging latency
  __syncthreads();                   // drains vmcnt; halo 0 + B(0,1) ready
  run27(0);

  issueB(0, 1, 0); issueB(1, 1, 1);  // half-1 B prologue (doesn't touch halo)
  __syncthreads();                   // all waves done reading half-0 halo
  stage_halo(1);
  __syncthreads();                   // halo 1 ready (drains everything)
  run27(1);

  // ---- epilogue: D row = x (within 16-frag), col = cout (round-1 verified) ----
  const int z = z0 + zo;
  #pragma unroll
  for (int nf = 0; nf < 4; ++nf) {
    int cout = nf * 16 + r15;
    float bv = bias[cout];
    #pragma unroll
    for (int mf = 0; mf < 4; ++mf) {
      int y  = y0 + yo2 + (mf >> 1);
      int x0 = (mf & 1) * 16 + 4 * hi4;
      float* orow = out + ((size_t)((b * 64 + cout) * 32 + z) * 32 + y) * 32;
      f32x4 v;
      #pragma unroll
      for (int r = 0; r < 4; ++r) v[r] = acc[mf][nf][r] + bv;
      *(f32x4*)&orow[x0] = v;
    }
  }
}

extern "C" void kernel_launch(void* const* d_in, const int* in_sizes, int n_in,
                              void* d_out, int out_size, void* d_ws, size_t ws_size,
                              hipStream_t stream) {
  const float* x    = (const float*)d_in[0];
  const float* wgt  = (const float*)d_in[1];
  const float* bias = (const float*)d_in[2];
  float* out = (float*)d_out;
  char* ws = (char*)d_ws;

  prep_kernel<<<4528, 256, 0, stream>>>(x, wgt,
                                        (unsigned short*)(ws + WS_W_OFF),
                                        (float*)(ws + WS_ZERO_OFF),
                                        (unsigned short*)(ws + WS_XT_OFF));
  conv_kernel<<<512, 256, 0, stream>>>(bias, out, ws);
}